// Round 1
// 122.140 us; speedup vs baseline: 1.0883x; 1.0883x over previous
//
#include <hip/hip_runtime.h>
#include <hip/hip_bf16.h>
#include <math.h>

// SphConv: B=64, n=32, C_in=C_out=128, L=16, (l,m) pairs l>=m: 136.
// Intermediates live inside d_out (chat per (b,o-quarter) strip, coef per
// (b,c-half) strip) — every k_bwd block's read-set is inside its own write
// region. dtype (fp32 vs bf16) detected from data (deterministic).
// k_chan uses MFMA 16x16x32 bf16 (coef/chat are bf16-packed anyway).
// k_bwd (this round): pair-minor LDS layout ([ol][pair]/[j][pair], pad 140)
// -> 34 ds_read_b128 + 34 broadcast float4 per thread instead of 544
// ds_read_b32; 1024 thr/block (1 output column/thread) -> 4 waves/SIMD.

#define NPAIR 136
#define PADC 140   // pair-minor row stride (136 + 4 pad, 16B-aligned rows)

typedef __attribute__((ext_vector_type(8))) short short8;
typedef __attribute__((ext_vector_type(4))) float f32x4;
#define MFMA16(A, B, C) __builtin_amdgcn_mfma_f32_16x16x32_bf16(A, B, C, 0, 0, 0)

static __device__ __forceinline__ float us2f(unsigned int u) {
  union { unsigned int i; float f; } v; v.i = u << 16; return v.f;
}
static __device__ __forceinline__ unsigned short f2us(float f) {
  __hip_bfloat16 h = __float2bfloat16(f);
  return *(unsigned short*)&h;
}
static __device__ __forceinline__ float lo_f(unsigned int pk) {
  union { unsigned int i; float f; } v; v.i = pk << 16; return v.f;
}
static __device__ __forceinline__ float hi_f(unsigned int pk) {
  union { unsigned int i; float f; } v; v.i = pk & 0xffff0000u; return v.f;
}
static __device__ __forceinline__ unsigned int packbf(float a, float b) {
  return (unsigned int)f2us(a) | ((unsigned int)f2us(b) << 16);
}

__device__ __align__(16) unsigned short g_atab_h[NPAIR * 32]; // bf16 Q*wj
__device__ __align__(16) float          g_stab[32 * PADC];    // fp32 Q*scale*(m?2:1), [j][pair]

static __device__ __forceinline__ int detect_fp32(const void* xin) {
  const unsigned short* u = (const unsigned short*)xin;
  int lane = threadIdx.x & 63;
  int big = 0;
#pragma unroll
  for (int q = 0; q < 4; ++q) {
    float v = us2f((unsigned int)u[lane * 8 + q * 2]);
    if (!(fabsf(v) <= 1e3f)) big = 1;
  }
  unsigned long long mask = __ballot(big);
  return (__popcll(mask) >= 16) ? 1 : 0;
}

// chat quarter: 4352 uints per (b,oq); wpr = 8*esz uints per 128-elem row.
static __device__ __forceinline__ size_t chat_q_byte(int b, int oq, int u, int esz) {
  int wpr = 8 * esz;
  int s = u / wpr, w = u % wpr;
  return ((size_t)b * 131072 + (size_t)s * 128 + oq * 32) * (size_t)esz + (size_t)w * 4;
}
// coef half: 8704 uints per (b,h); wpr = 16*esz; rows start at 544/esz.
static __device__ __forceinline__ size_t coef_byte(int b, int h, int u, int esz) {
  int wpr = 16 * esz;
  int s = 544 / esz + u / wpr, w = u % wpr;
  return ((size_t)b * 131072 + (size_t)s * 128 + h * 64) * (size_t)esz + (size_t)w * 4;
}

// 32-pt DFT trig tables, cos/sin(2*pi*k/32) — compile-time indices only
#define DEF_TRIG \
  constexpr float CT[32] = { \
    1.0f, 0.98078528f, 0.92387953f, 0.83146961f, 0.70710678f, 0.55557023f, \
    0.38268343f, 0.19509032f, 0.0f, -0.19509032f, -0.38268343f, -0.55557023f, \
    -0.70710678f, -0.83146961f, -0.92387953f, -0.98078528f, -1.0f, \
    -0.98078528f, -0.92387953f, -0.83146961f, -0.70710678f, -0.55557023f, \
    -0.38268343f, -0.19509032f, 0.0f, 0.19509032f, 0.38268343f, 0.55557023f, \
    0.70710678f, 0.83146961f, 0.92387953f, 0.98078528f }; \
  constexpr float ST[32] = { \
    0.0f, 0.19509032f, 0.38268343f, 0.55557023f, 0.70710678f, 0.83146961f, \
    0.92387953f, 0.98078528f, 1.0f, 0.98078528f, 0.92387953f, 0.83146961f, \
    0.70710678f, 0.55557023f, 0.38268343f, 0.19509032f, 0.0f, \
    -0.19509032f, -0.38268343f, -0.55557023f, -0.70710678f, -0.83146961f, \
    -0.92387953f, -0.98078528f, -1.0f, -0.98078528f, -0.92387953f, \
    -0.83146961f, -0.70710678f, -0.55557023f, -0.38268343f, -0.19509032f }

// ---------------------------------------------------------------------------
// K0: tables. One block per (l,m) pair x 32 j.
// ---------------------------------------------------------------------------
__global__ void k_init() {
  const int pair = blockIdx.x, j = threadIdx.x;
  int m = 0;
#pragma unroll
  for (int mm = 1; mm < 16; ++mm) {
    int off = mm * 16 - (mm * (mm - 1)) / 2;
    if (off <= pair) m = mm;
  }
  const int l = m + (pair - (m * 16 - (m * (m - 1)) / 2));
  double theta = M_PI * (j + 0.5) / 32.0;
  double x = cos(theta), sx = sin(theta);
  double wj = sx * (M_PI / 32.0) * (2.0 * M_PI / 32.0);
  double pmm = 1.0;
  for (int k = 1; k <= m; ++k) pmm *= -(2.0 * k - 1.0) * sx;
  double p = pmm, pl1 = 0.0, pl2 = 0.0;
  for (int ll = m; ll <= l; ++ll) {
    if (ll == m)          p = pmm;
    else if (ll == m + 1) p = (2.0 * m + 1.0) * x * pmm;
    else                  p = ((2.0 * ll - 1.0) * x * pl1 - (double)(ll + m - 1) * pl2) / (double)(ll - m);
    pl2 = pl1; pl1 = p;
  }
  double r = 1.0;
  for (int k = l - m + 1; k <= l + m; ++k) r *= (double)k;   // (l+m)!/(l-m)!
  double Nlm = sqrt((2.0 * l + 1.0) / (4.0 * M_PI) / r);
  g_atab_h[pair * 32 + j] = f2us((float)(Nlm * p * wj));
  g_stab[j * PADC + pair] = (float)(Nlm * p * (2.0 * M_PI * sqrt(4.0 * M_PI / (2.0 * l + 1.0)))
                                    * (m ? 2.0 : 1.0));
}

// ---------------------------------------------------------------------------
// K1: fused FFT(phi) + Legendre analysis -> coef. 1024 blocks x 256 thr,
// block=(b, 8-ch group), XCD-swizzled. LDS 35 KB -> 4 blocks/CU.
// Phase 1: one (j,c) DFT per thread. Phase 2: (m,c,jh), atab from global.
// ---------------------------------------------------------------------------
__global__ __launch_bounds__(256) void k_fwd(const void* __restrict__ xin,
                                             char* __restrict__ outbuf) {
  const int fp32m = detect_fp32(xin);
  const int esz = fp32m ? 4 : 2;
  __shared__ __align__(16) unsigned short xs[32 * 264];    // [p][j*8+c]
  __shared__ __align__(16) unsigned int   fsp[128 * 36];   // [(m*8+c)][j] re|im bf16
  const int blk = blockIdx.x;
  const int b = (blk & 7) | (((blk >> 7) & 7) << 3);       // same-b -> same XCD
  const int cq = (blk >> 3) & 15;                          // 8-channel group
  const int t = threadIdx.x;
  if (fp32m) {
    const float* xf = (const float*)xin;
#pragma unroll
    for (int it = 0; it < 8; ++it) {
      int i = t + it * 256;                                // [0,2048)
      int s = i >> 1, hf = i & 1;
      float4 v = *(const float4*)(xf + ((size_t)b * 1024 + s) * 128 + cq * 8 + hf * 4);
      int p = s & 31, j = s >> 5;
      *(uint2*)&xs[p * 264 + j * 8 + hf * 4] = make_uint2(packbf(v.x, v.y), packbf(v.z, v.w));
    }
  } else {
    const unsigned short* xh = (const unsigned short*)xin;
#pragma unroll
    for (int it = 0; it < 4; ++it) {
      int s = t + it * 256;                                // [0,1024)
      uint4 v = *(const uint4*)(xh + ((size_t)b * 1024 + s) * 128 + cq * 8);
      int p = s & 31, j = s >> 5;
      *(uint4*)&xs[p * 264 + j * 8] = v;
    }
  }
  __syncthreads();
  {   // phase 1: one 32-pt real DFT per thread. thread = (j, c).
    DEF_TRIG;
    const int j = t >> 3, c = t & 7, rb = j * 8 + c;
    float x0  = us2f((unsigned int)xs[rb]);
    float x16 = us2f((unsigned int)xs[16 * 264 + rb]);
    float sp[16], dm[16];
#pragma unroll
    for (int p = 1; p <= 15; ++p) {
      float a  = us2f((unsigned int)xs[p * 264 + rb]);
      float bq = us2f((unsigned int)xs[(32 - p) * 264 + rb]);
      sp[p] = a + bq; dm[p] = a - bq;
    }
#pragma unroll
    for (int mi = 0; mi < 16; ++mi) {
      float re = x0 + ((mi & 1) ? -x16 : x16);
      float im = 0.f;
#pragma unroll
      for (int p = 1; p <= 15; ++p) {
        re += sp[p] * CT[(mi * p) & 31];
        im -= dm[p] * ST[(mi * p) & 31];
      }
      fsp[(mi * 8 + c) * 36 + j] = packbf(re, im);
    }
  }
  __syncthreads();
  {   // phase 2: quadrature. thread = (m, c, jh); F = 4 uint4; atab global.
    const int m = t >> 4, c = (t >> 1) & 7, jh = t & 1;
    const int cg = cq * 8 + c, h = cg >> 6, cl = cg & 63;
    const int base = m * 16 - (m * (m - 1)) / 2;
    uint4 F[4];
#pragma unroll
    for (int q = 0; q < 4; ++q)
      F[q] = *(const uint4*)&fsp[(m * 8 + c) * 36 + jh * 16 + q * 4];
    for (int l = m; l < 16; ++l) {
      int pair = base + (l - m);
      float sr = 0.f, si = 0.f;
#pragma unroll
      for (int q = 0; q < 2; ++q) {
        uint4 a = *(const uint4*)&g_atab_h[pair * 32 + jh * 16 + q * 8];
        float a0 = us2f(a.x & 0xffff), a1 = us2f(a.x >> 16);
        float a2 = us2f(a.y & 0xffff), a3 = us2f(a.y >> 16);
        float a4 = us2f(a.z & 0xffff), a5 = us2f(a.z >> 16);
        float a6 = us2f(a.w & 0xffff), a7 = us2f(a.w >> 16);
        uint4 f0 = F[2 * q], f1 = F[2 * q + 1];
        sr += a0 * lo_f(f0.x) + a1 * lo_f(f0.y) + a2 * lo_f(f0.z) + a3 * lo_f(f0.w)
            + a4 * lo_f(f1.x) + a5 * lo_f(f1.y) + a6 * lo_f(f1.z) + a7 * lo_f(f1.w);
        si += a0 * hi_f(f0.x) + a1 * hi_f(f0.y) + a2 * hi_f(f0.z) + a3 * hi_f(f0.w)
            + a4 * hi_f(f1.x) + a5 * hi_f(f1.y) + a6 * hi_f(f1.z) + a7 * hi_f(f1.w);
      }
      sr += __shfl_xor(sr, 1, 64);
      si += __shfl_xor(si, 1, 64);
      if (jh == 0) {
        int u = pair * 64 + cl;
        *(unsigned int*)(outbuf + coef_byte(b, h, u, esz)) = packbf(sr, si);
      }
    }
  }
}

// ---------------------------------------------------------------------------
// K2: channel GEMM via MFMA 16x16x32 bf16. Block=(pair, b-half, o-half):
// M=32(b), N=64(o), K=128(c), re+im sharing W fragments. 544 blocks x 256 thr.
// A[m=lane&15][k=quad*8+j], B[k=quad*8+j][n=lane&15], D col=lane&15,
// row=quad*4+reg (verified gfx950 mappings).
// ---------------------------------------------------------------------------
__global__ __launch_bounds__(256) void k_chan(char* __restrict__ outbuf,
                                              const void* __restrict__ Wv,
                                              const void* __restrict__ xin) {
  const int fp32m = detect_fp32(xin);
  const int esz = fp32m ? 4 : 2;
  const int pair = blockIdx.x >> 2;
  const int bh = (blockIdx.x >> 1) & 1, otile = blockIdx.x & 1;
  int m = 0;
#pragma unroll
  for (int mm = 1; mm < 16; ++mm) {
    int off = mm * 16 - (mm * (mm - 1)) / 2;
    if (off <= pair) m = mm;
  }
  const int l = m + (pair - (m * 16 - (m * (m - 1)) / 2));
  __shared__ __align__(16) unsigned short Xr[32 * 136];   // [b'][c] bf16
  __shared__ __align__(16) unsigned short Xi[32 * 136];
  __shared__ __align__(16) unsigned short Wt[64 * 136];   // [o'][c] bf16 (transposed)
  const int t = threadIdx.x;
  // stage coef (packed re|im uints in both modes)
  for (int i = t; i < 4096; i += 256) {
    int bl = i >> 7, c = i & 127;
    unsigned int pk = *(const unsigned int*)(outbuf +
        coef_byte(bh * 32 + bl, c >> 6, pair * 64 + (c & 63), esz));
    Xr[bl * 136 + c] = (unsigned short)(pk & 0xffff);
    Xi[bl * 136 + c] = (unsigned short)(pk >> 16);
  }
  // stage W transposed: Wt[o'][c], o' in [0,64)
  for (int i = t; i < 1024; i += 256) {
    int c = i >> 3, og = i & 7;
    size_t widx = (size_t)c * 2048 + l * 128 + otile * 64 + og * 8;
    if (fp32m) {
      const float* Wf = (const float*)Wv;
      float4 f0 = *(const float4*)(Wf + widx);
      float4 f1 = *(const float4*)(Wf + widx + 4);
      Wt[(og * 8 + 0) * 136 + c] = f2us(f0.x); Wt[(og * 8 + 1) * 136 + c] = f2us(f0.y);
      Wt[(og * 8 + 2) * 136 + c] = f2us(f0.z); Wt[(og * 8 + 3) * 136 + c] = f2us(f0.w);
      Wt[(og * 8 + 4) * 136 + c] = f2us(f1.x); Wt[(og * 8 + 5) * 136 + c] = f2us(f1.y);
      Wt[(og * 8 + 6) * 136 + c] = f2us(f1.z); Wt[(og * 8 + 7) * 136 + c] = f2us(f1.w);
    } else {
      const unsigned short* Wh = (const unsigned short*)Wv;
      uint4 v = *(const uint4*)(Wh + widx);
      Wt[(og * 8 + 0) * 136 + c] = (unsigned short)(v.x & 0xffff);
      Wt[(og * 8 + 1) * 136 + c] = (unsigned short)(v.x >> 16);
      Wt[(og * 8 + 2) * 136 + c] = (unsigned short)(v.y & 0xffff);
      Wt[(og * 8 + 3) * 136 + c] = (unsigned short)(v.y >> 16);
      Wt[(og * 8 + 4) * 136 + c] = (unsigned short)(v.z & 0xffff);
      Wt[(og * 8 + 5) * 136 + c] = (unsigned short)(v.z >> 16);
      Wt[(og * 8 + 6) * 136 + c] = (unsigned short)(v.w & 0xffff);
      Wt[(og * 8 + 7) * 136 + c] = (unsigned short)(v.w >> 16);
    }
  }
  __syncthreads();
  // MFMA: wave -> (mtile = w&1, n-group = w>>1 covering 2 n-tiles)
  const int wv = t >> 6, lane = t & 63;
  const int col = lane & 15, quad = lane >> 4;
  const int mtile = wv & 1, ng = wv >> 1;
  f32x4 accR0 = {0.f, 0.f, 0.f, 0.f}, accI0 = accR0, accR1 = accR0, accI1 = accR0;
#pragma unroll
  for (int kc = 0; kc < 4; ++kc) {
    short8 Ar = *(const short8*)&Xr[(mtile * 16 + col) * 136 + kc * 32 + quad * 8];
    short8 Ai = *(const short8*)&Xi[(mtile * 16 + col) * 136 + kc * 32 + quad * 8];
    short8 B0 = *(const short8*)&Wt[(ng * 32 + col) * 136 + kc * 32 + quad * 8];
    short8 B1 = *(const short8*)&Wt[(ng * 32 + 16 + col) * 136 + kc * 32 + quad * 8];
    accR0 = MFMA16(Ar, B0, accR0);
    accI0 = MFMA16(Ai, B0, accI0);
    accR1 = MFMA16(Ar, B1, accR1);
    accI1 = MFMA16(Ai, B1, accI1);
  }
  // epilogue: D col=lane&15, row=quad*4+reg
#pragma unroll
  for (int reg = 0; reg < 4; ++reg) {
    int bb = bh * 32 + mtile * 16 + quad * 4 + reg;
    int o0 = otile * 64 + ng * 32 + col;
    int o1 = o0 + 16;
    *(unsigned int*)(outbuf + chat_q_byte(bb, o0 >> 5, pair * 32 + (o0 & 31), esz)) =
        packbf(accR0[reg], accI0[reg]);
    *(unsigned int*)(outbuf + chat_q_byte(bb, o1 >> 5, pair * 32 + (o1 & 31), esz)) =
        packbf(accR1[reg], accI1[reg]);
  }
}

// ---------------------------------------------------------------------------
// K3: fused Legendre synthesis + inverse DFT + bias. Block=(b, o-quarter):
// 256 blocks x 1024 thr, thread=(j, one o). Pair-minor LDS: chs[ol][pair],
// stb[j][pair] (stride PADC=140) -> 34 ds_read_b128 + 34 broadcast float4
// per thread (was 544 ds_read_b32); 4 waves/SIMD (was 2).
// ---------------------------------------------------------------------------
__global__ __launch_bounds__(1024) void k_bwd(char* __restrict__ outbuf,
                                              const void* __restrict__ biasv,
                                              const void* __restrict__ xin) {
  const int fp32m = detect_fp32(xin);
  const int esz = fp32m ? 4 : 2;
  __shared__ __align__(16) unsigned int chs[32 * PADC];    // [ol][pair] re|im bf16
  __shared__ __align__(16) float        stb[32 * PADC];    // [j][pair]
  const int b = blockIdx.x >> 2, oq = blockIdx.x & 3;
  const int t = threadIdx.x;
  for (int i = t; i < NPAIR * 8; i += 1024) {              // 1088 uint4, transpose
    uint4 v = *(const uint4*)(outbuf + chat_q_byte(b, oq, i * 4, esz));
    const int pair = i >> 3, ol0 = (i & 7) * 4;            // u = pair*32 + ol0
    chs[(ol0 + 0) * PADC + pair] = v.x;
    chs[(ol0 + 1) * PADC + pair] = v.y;
    chs[(ol0 + 2) * PADC + pair] = v.z;
    chs[(ol0 + 3) * PADC + pair] = v.w;
  }
  for (int i = t; i < 32 * PADC / 4; i += 1024)            // g_stab already [j][pair]
    ((float4*)stb)[i] = ((const float4*)g_stab)[i];
  const int j = t >> 5, ol = t & 31;
  const int o = oq * 32 + ol;
  const float bv = fp32m ? ((const float*)biasv)[o]
                         : us2f((unsigned int)((const unsigned short*)biasv)[o]);
  __syncthreads();

  float Gr[16], Gi[16];
#pragma unroll
  for (int mm = 0; mm < 16; ++mm) { Gr[mm] = 0.f; Gi[mm] = 0.f; }
  {
    float4 s4 = {0.f, 0.f, 0.f, 0.f};
    uint4  c4 = {0u, 0u, 0u, 0u};
    int pair = 0;
#pragma unroll
    for (int mm = 0; mm < 16; ++mm) {
#pragma unroll
      for (int l = mm; l < 16; ++l) {
        if ((pair & 3) == 0) {                             // folds: pair is unroll-const
          s4 = *(const float4*)&stb[j * PADC + pair];
          c4 = *(const uint4*)&chs[ol * PADC + pair];
        }
        const int r = pair & 3;
        const float        s  = (r == 0) ? s4.x : (r == 1) ? s4.y : (r == 2) ? s4.z : s4.w;
        const unsigned int cv = (r == 0) ? c4.x : (r == 1) ? c4.y : (r == 2) ? c4.z : c4.w;
        Gr[mm] += s * lo_f(cv);
        Gi[mm] += s * hi_f(cv);
        ++pair;
      }
    }
  }
  DEF_TRIG;
#pragma unroll
  for (int pp = 0; pp <= 16; ++pp) {
    float A = 0.f, Bv = 0.f;
#pragma unroll
    for (int mm = 0; mm < 16; ++mm) {
      A  += Gr[mm] * CT[(mm * pp) & 31];
      Bv += Gi[mm] * ST[(mm * pp) & 31];
    }
    const int p2 = (32 - pp) & 31;
    size_t e1 = (size_t)b * 131072 + (size_t)(j * 32 + pp) * 128 + o;
    size_t e2 = (size_t)b * 131072 + (size_t)(j * 32 + p2) * 128 + o;
    if (fp32m) {
      *(float*)(outbuf + e1 * 4) = bv + A - Bv;
      *(float*)(outbuf + e2 * 4) = bv + A + Bv;
    } else {
      *(unsigned short*)(outbuf + e1 * 2) = f2us(bv + A - Bv);
      *(unsigned short*)(outbuf + e2 * 2) = f2us(bv + A + Bv);
    }
  }
}

// ---------------------------------------------------------------------------
extern "C" void kernel_launch(void* const* d_in, const int* in_sizes, int n_in,
                              void* d_out, int out_size, void* d_ws, size_t ws_size,
                              hipStream_t stream) {
  const void* xin  = d_in[0];   // (64,32,32,128) fp32 or bf16 (auto-detected)
  const void* W    = d_in[1];   // (128,16,128)
  const void* bias = d_in[2];   // (128)
  char* out = (char*)d_out;

  hipLaunchKernelGGL(k_init, dim3(NPAIR), dim3(32),   0, stream);
  hipLaunchKernelGGL(k_fwd,  dim3(1024),  dim3(256),  0, stream, xin, out);
  hipLaunchKernelGGL(k_chan, dim3(544),   dim3(256),  0, stream, out, W, xin);
  hipLaunchKernelGGL(k_bwd,  dim3(256),   dim3(1024), 0, stream, out, bias, xin);
}

// Round 2
// 118.084 us; speedup vs baseline: 1.1257x; 1.0344x over previous
//
#include <hip/hip_runtime.h>
#include <hip/hip_bf16.h>
#include <math.h>

// SphConv: B=64, n=32, C_in=C_out=128, L=16, (l,m) pairs l>=m: 136.
// Intermediates live inside d_out (chat per (b,o-quarter) strip, coef per
// (b,c-half) strip) — every k_bwd block's read-set is inside its own write
// region. dtype (fp32 vs bf16) detected from data (deterministic).
// k_chan uses MFMA 16x16x32 bf16 (coef/chat are bf16-packed anyway).
// This round: (1) k_fwd stages atab into the dead xs LDS region (prefetched
// to regs during input staging) — kills 17x2 global table loads in the
// l-loop; (2) k_chan coef staging vectorized to uint4; (3) k_init memoized
// via g_tab_ready (tables are input-independent constants).

#define NPAIR 136
#define PADC 140   // pair-minor row stride (136 + 4 pad, 16B-aligned rows)

typedef __attribute__((ext_vector_type(8))) short short8;
typedef __attribute__((ext_vector_type(4))) float f32x4;
#define MFMA16(A, B, C) __builtin_amdgcn_mfma_f32_16x16x32_bf16(A, B, C, 0, 0, 0)

static __device__ __forceinline__ float us2f(unsigned int u) {
  union { unsigned int i; float f; } v; v.i = u << 16; return v.f;
}
static __device__ __forceinline__ unsigned short f2us(float f) {
  __hip_bfloat16 h = __float2bfloat16(f);
  return *(unsigned short*)&h;
}
static __device__ __forceinline__ float lo_f(unsigned int pk) {
  union { unsigned int i; float f; } v; v.i = pk << 16; return v.f;
}
static __device__ __forceinline__ float hi_f(unsigned int pk) {
  union { unsigned int i; float f; } v; v.i = pk & 0xffff0000u; return v.f;
}
static __device__ __forceinline__ unsigned int packbf(float a, float b) {
  return (unsigned int)f2us(a) | ((unsigned int)f2us(b) << 16);
}

__device__ __align__(16) unsigned short g_atab_h[NPAIR * 32]; // bf16 Q*wj
__device__ __align__(16) float          g_stab[32 * PADC];    // fp32 Q*scale*(m?2:1), [j][pair]
__device__ int g_tab_ready;                                   // tables memoized across runs

static __device__ __forceinline__ int detect_fp32(const void* xin) {
  const unsigned short* u = (const unsigned short*)xin;
  int lane = threadIdx.x & 63;
  int big = 0;
#pragma unroll
  for (int q = 0; q < 4; ++q) {
    float v = us2f((unsigned int)u[lane * 8 + q * 2]);
    if (!(fabsf(v) <= 1e3f)) big = 1;
  }
  unsigned long long mask = __ballot(big);
  return (__popcll(mask) >= 16) ? 1 : 0;
}

// chat quarter: 4352 uints per (b,oq); wpr = 8*esz uints per 128-elem row.
static __device__ __forceinline__ size_t chat_q_byte(int b, int oq, int u, int esz) {
  int wpr = 8 * esz;
  int s = u / wpr, w = u % wpr;
  return ((size_t)b * 131072 + (size_t)s * 128 + oq * 32) * (size_t)esz + (size_t)w * 4;
}
// coef half: 8704 uints per (b,h); wpr = 16*esz; rows start at 544/esz.
static __device__ __forceinline__ size_t coef_byte(int b, int h, int u, int esz) {
  int wpr = 16 * esz;
  int s = 544 / esz + u / wpr, w = u % wpr;
  return ((size_t)b * 131072 + (size_t)s * 128 + h * 64) * (size_t)esz + (size_t)w * 4;
}

// 32-pt DFT trig tables, cos/sin(2*pi*k/32) — compile-time indices only
#define DEF_TRIG \
  constexpr float CT[32] = { \
    1.0f, 0.98078528f, 0.92387953f, 0.83146961f, 0.70710678f, 0.55557023f, \
    0.38268343f, 0.19509032f, 0.0f, -0.19509032f, -0.38268343f, -0.55557023f, \
    -0.70710678f, -0.83146961f, -0.92387953f, -0.98078528f, -1.0f, \
    -0.98078528f, -0.92387953f, -0.83146961f, -0.70710678f, -0.55557023f, \
    -0.38268343f, -0.19509032f, 0.0f, 0.19509032f, 0.38268343f, 0.55557023f, \
    0.70710678f, 0.83146961f, 0.92387953f, 0.98078528f }; \
  constexpr float ST[32] = { \
    0.0f, 0.19509032f, 0.38268343f, 0.55557023f, 0.70710678f, 0.83146961f, \
    0.92387953f, 0.98078528f, 1.0f, 0.98078528f, 0.92387953f, 0.83146961f, \
    0.70710678f, 0.55557023f, 0.38268343f, 0.19509032f, 0.0f, \
    -0.19509032f, -0.38268343f, -0.55557023f, -0.70710678f, -0.83146961f, \
    -0.92387953f, -0.98078528f, -1.0f, -0.98078528f, -0.92387953f, \
    -0.83146961f, -0.70710678f, -0.55557023f, -0.38268343f, -0.19509032f }

// ---------------------------------------------------------------------------
// K0: tables. One block per (l,m) pair x 32 j. Memoized via g_tab_ready.
// ---------------------------------------------------------------------------
__global__ void k_init() {
  if (g_tab_ready) return;                                 // constants persist
  const int pair = blockIdx.x, j = threadIdx.x;
  int m = 0;
#pragma unroll
  for (int mm = 1; mm < 16; ++mm) {
    int off = mm * 16 - (mm * (mm - 1)) / 2;
    if (off <= pair) m = mm;
  }
  const int l = m + (pair - (m * 16 - (m * (m - 1)) / 2));
  double theta = M_PI * (j + 0.5) / 32.0;
  double x = cos(theta), sx = sin(theta);
  double wj = sx * (M_PI / 32.0) * (2.0 * M_PI / 32.0);
  double pmm = 1.0;
  for (int k = 1; k <= m; ++k) pmm *= -(2.0 * k - 1.0) * sx;
  double p = pmm, pl1 = 0.0, pl2 = 0.0;
  for (int ll = m; ll <= l; ++ll) {
    if (ll == m)          p = pmm;
    else if (ll == m + 1) p = (2.0 * m + 1.0) * x * pmm;
    else                  p = ((2.0 * ll - 1.0) * x * pl1 - (double)(ll + m - 1) * pl2) / (double)(ll - m);
    pl2 = pl1; pl1 = p;
  }
  double r = 1.0;
  for (int k = l - m + 1; k <= l + m; ++k) r *= (double)k;   // (l+m)!/(l-m)!
  double Nlm = sqrt((2.0 * l + 1.0) / (4.0 * M_PI) / r);
  g_atab_h[pair * 32 + j] = f2us((float)(Nlm * p * wj));
  g_stab[j * PADC + pair] = (float)(Nlm * p * (2.0 * M_PI * sqrt(4.0 * M_PI / (2.0 * l + 1.0)))
                                    * (m ? 2.0 : 1.0));
  if (pair == NPAIR - 1 && j == 31) g_tab_ready = 1;       // visible next launch
}

// ---------------------------------------------------------------------------
// K1: fused FFT(phi) + Legendre analysis -> coef. 1024 blocks x 256 thr,
// block=(b, 8-ch group), XCD-swizzled. LDS 35 KB -> 4 blocks/CU.
// Phase 1: one (j,c) DFT per thread. Phase 2: (m,c,jh); atab in LDS (xs
// region reused — prefetched to regs during input staging, written after
// the phase-1 barrier).
// ---------------------------------------------------------------------------
__global__ __launch_bounds__(256) void k_fwd(const void* __restrict__ xin,
                                             char* __restrict__ outbuf) {
  const int fp32m = detect_fp32(xin);
  const int esz = fp32m ? 4 : 2;
  __shared__ __align__(16) unsigned short xs[32 * 264];    // [p][j*8+c]; atab after ph1
  __shared__ __align__(16) unsigned int   fsp[128 * 36];   // [(m*8+c)][j] re|im bf16
  const int blk = blockIdx.x;
  const int b = (blk & 7) | (((blk >> 7) & 7) << 3);       // same-b -> same XCD
  const int cq = (blk >> 3) & 15;                          // 8-channel group
  const int t = threadIdx.x;
  // prefetch atab (544 uint4) into registers — latency hides under phase 1
  uint4 at0 = ((const uint4*)g_atab_h)[t];
  uint4 at1 = ((const uint4*)g_atab_h)[t + 256];
  uint4 at2;
  if (t < 32) at2 = ((const uint4*)g_atab_h)[512 + t];
  if (fp32m) {
    const float* xf = (const float*)xin;
#pragma unroll
    for (int it = 0; it < 8; ++it) {
      int i = t + it * 256;                                // [0,2048)
      int s = i >> 1, hf = i & 1;
      float4 v = *(const float4*)(xf + ((size_t)b * 1024 + s) * 128 + cq * 8 + hf * 4);
      int p = s & 31, j = s >> 5;
      *(uint2*)&xs[p * 264 + j * 8 + hf * 4] = make_uint2(packbf(v.x, v.y), packbf(v.z, v.w));
    }
  } else {
    const unsigned short* xh = (const unsigned short*)xin;
#pragma unroll
    for (int it = 0; it < 4; ++it) {
      int s = t + it * 256;                                // [0,1024)
      uint4 v = *(const uint4*)(xh + ((size_t)b * 1024 + s) * 128 + cq * 8);
      int p = s & 31, j = s >> 5;
      *(uint4*)&xs[p * 264 + j * 8] = v;
    }
  }
  __syncthreads();
  {   // phase 1: one 32-pt real DFT per thread. thread = (j, c).
    DEF_TRIG;
    const int j = t >> 3, c = t & 7, rb = j * 8 + c;
    float x0  = us2f((unsigned int)xs[rb]);
    float x16 = us2f((unsigned int)xs[16 * 264 + rb]);
    float sp[16], dm[16];
#pragma unroll
    for (int p = 1; p <= 15; ++p) {
      float a  = us2f((unsigned int)xs[p * 264 + rb]);
      float bq = us2f((unsigned int)xs[(32 - p) * 264 + rb]);
      sp[p] = a + bq; dm[p] = a - bq;
    }
#pragma unroll
    for (int mi = 0; mi < 16; ++mi) {
      float re = x0 + ((mi & 1) ? -x16 : x16);
      float im = 0.f;
#pragma unroll
      for (int p = 1; p <= 15; ++p) {
        re += sp[p] * CT[(mi * p) & 31];
        im -= dm[p] * ST[(mi * p) & 31];
      }
      fsp[(mi * 8 + c) * 36 + j] = packbf(re, im);
    }
  }
  __syncthreads();                                         // xs dead; fsp ready
  ((uint4*)xs)[t] = at0;                                   // stage atab into xs
  ((uint4*)xs)[t + 256] = at1;
  if (t < 32) ((uint4*)xs)[512 + t] = at2;
  __syncthreads();
  {   // phase 2: quadrature. thread = (m, c, jh); F = 4 uint4; atab in LDS.
    const int m = t >> 4, c = (t >> 1) & 7, jh = t & 1;
    const int cg = cq * 8 + c, h = cg >> 6, cl = cg & 63;
    const int base = m * 16 - (m * (m - 1)) / 2;
    uint4 F[4];
#pragma unroll
    for (int q = 0; q < 4; ++q)
      F[q] = *(const uint4*)&fsp[(m * 8 + c) * 36 + jh * 16 + q * 4];
    for (int l = m; l < 16; ++l) {
      int pair = base + (l - m);
      float sr = 0.f, si = 0.f;
#pragma unroll
      for (int q = 0; q < 2; ++q) {
        uint4 a = ((const uint4*)xs)[pair * 4 + jh * 2 + q];
        float a0 = us2f(a.x & 0xffff), a1 = us2f(a.x >> 16);
        float a2 = us2f(a.y & 0xffff), a3 = us2f(a.y >> 16);
        float a4 = us2f(a.z & 0xffff), a5 = us2f(a.z >> 16);
        float a6 = us2f(a.w & 0xffff), a7 = us2f(a.w >> 16);
        uint4 f0 = F[2 * q], f1 = F[2 * q + 1];
        sr += a0 * lo_f(f0.x) + a1 * lo_f(f0.y) + a2 * lo_f(f0.z) + a3 * lo_f(f0.w)
            + a4 * lo_f(f1.x) + a5 * lo_f(f1.y) + a6 * lo_f(f1.z) + a7 * lo_f(f1.w);
        si += a0 * hi_f(f0.x) + a1 * hi_f(f0.y) + a2 * hi_f(f0.z) + a3 * hi_f(f0.w)
            + a4 * hi_f(f1.x) + a5 * hi_f(f1.y) + a6 * hi_f(f1.z) + a7 * hi_f(f1.w);
      }
      sr += __shfl_xor(sr, 1, 64);
      si += __shfl_xor(si, 1, 64);
      if (jh == 0) {
        int u = pair * 64 + cl;
        *(unsigned int*)(outbuf + coef_byte(b, h, u, esz)) = packbf(sr, si);
      }
    }
  }
}

// ---------------------------------------------------------------------------
// K2: channel GEMM via MFMA 16x16x32 bf16. Block=(pair, b-half, o-half):
// M=32(b), N=64(o), K=128(c), re+im sharing W fragments. 544 blocks x 256 thr.
// A[m=lane&15][k=quad*8+j], B[k=quad*8+j][n=lane&15], D col=lane&15,
// row=quad*4+reg (verified gfx950 mappings). coef staging now uint4.
// ---------------------------------------------------------------------------
__global__ __launch_bounds__(256) void k_chan(char* __restrict__ outbuf,
                                              const void* __restrict__ Wv,
                                              const void* __restrict__ xin) {
  const int fp32m = detect_fp32(xin);
  const int esz = fp32m ? 4 : 2;
  const int pair = blockIdx.x >> 2;
  const int bh = (blockIdx.x >> 1) & 1, otile = blockIdx.x & 1;
  int m = 0;
#pragma unroll
  for (int mm = 1; mm < 16; ++mm) {
    int off = mm * 16 - (mm * (mm - 1)) / 2;
    if (off <= pair) m = mm;
  }
  const int l = m + (pair - (m * 16 - (m * (m - 1)) / 2));
  __shared__ __align__(16) unsigned short Xr[32 * 136];   // [b'][c] bf16
  __shared__ __align__(16) unsigned short Xi[32 * 136];
  __shared__ __align__(16) unsigned short Wt[64 * 136];   // [o'][c] bf16 (transposed)
  const int t = threadIdx.x;
  // stage coef (packed re|im uints, 4-consecutive-c vectorized)
  for (int i = t; i < 1024; i += 256) {
    int bl = i >> 5, c4 = (i & 31) * 4;
    uint4 pk = *(const uint4*)(outbuf +
        coef_byte(bh * 32 + bl, c4 >> 6, pair * 64 + (c4 & 63), esz));
    Xr[bl * 136 + c4 + 0] = (unsigned short)(pk.x & 0xffff);
    Xi[bl * 136 + c4 + 0] = (unsigned short)(pk.x >> 16);
    Xr[bl * 136 + c4 + 1] = (unsigned short)(pk.y & 0xffff);
    Xi[bl * 136 + c4 + 1] = (unsigned short)(pk.y >> 16);
    Xr[bl * 136 + c4 + 2] = (unsigned short)(pk.z & 0xffff);
    Xi[bl * 136 + c4 + 2] = (unsigned short)(pk.z >> 16);
    Xr[bl * 136 + c4 + 3] = (unsigned short)(pk.w & 0xffff);
    Xi[bl * 136 + c4 + 3] = (unsigned short)(pk.w >> 16);
  }
  // stage W transposed: Wt[o'][c], o' in [0,64)
  for (int i = t; i < 1024; i += 256) {
    int c = i >> 3, og = i & 7;
    size_t widx = (size_t)c * 2048 + l * 128 + otile * 64 + og * 8;
    if (fp32m) {
      const float* Wf = (const float*)Wv;
      float4 f0 = *(const float4*)(Wf + widx);
      float4 f1 = *(const float4*)(Wf + widx + 4);
      Wt[(og * 8 + 0) * 136 + c] = f2us(f0.x); Wt[(og * 8 + 1) * 136 + c] = f2us(f0.y);
      Wt[(og * 8 + 2) * 136 + c] = f2us(f0.z); Wt[(og * 8 + 3) * 136 + c] = f2us(f0.w);
      Wt[(og * 8 + 4) * 136 + c] = f2us(f1.x); Wt[(og * 8 + 5) * 136 + c] = f2us(f1.y);
      Wt[(og * 8 + 6) * 136 + c] = f2us(f1.z); Wt[(og * 8 + 7) * 136 + c] = f2us(f1.w);
    } else {
      const unsigned short* Wh = (const unsigned short*)Wv;
      uint4 v = *(const uint4*)(Wh + widx);
      Wt[(og * 8 + 0) * 136 + c] = (unsigned short)(v.x & 0xffff);
      Wt[(og * 8 + 1) * 136 + c] = (unsigned short)(v.x >> 16);
      Wt[(og * 8 + 2) * 136 + c] = (unsigned short)(v.y & 0xffff);
      Wt[(og * 8 + 3) * 136 + c] = (unsigned short)(v.y >> 16);
      Wt[(og * 8 + 4) * 136 + c] = (unsigned short)(v.z & 0xffff);
      Wt[(og * 8 + 5) * 136 + c] = (unsigned short)(v.z >> 16);
      Wt[(og * 8 + 6) * 136 + c] = (unsigned short)(v.w & 0xffff);
      Wt[(og * 8 + 7) * 136 + c] = (unsigned short)(v.w >> 16);
    }
  }
  __syncthreads();
  // MFMA: wave -> (mtile = w&1, n-group = w>>1 covering 2 n-tiles)
  const int wv = t >> 6, lane = t & 63;
  const int col = lane & 15, quad = lane >> 4;
  const int mtile = wv & 1, ng = wv >> 1;
  f32x4 accR0 = {0.f, 0.f, 0.f, 0.f}, accI0 = accR0, accR1 = accR0, accI1 = accR0;
#pragma unroll
  for (int kc = 0; kc < 4; ++kc) {
    short8 Ar = *(const short8*)&Xr[(mtile * 16 + col) * 136 + kc * 32 + quad * 8];
    short8 Ai = *(const short8*)&Xi[(mtile * 16 + col) * 136 + kc * 32 + quad * 8];
    short8 B0 = *(const short8*)&Wt[(ng * 32 + col) * 136 + kc * 32 + quad * 8];
    short8 B1 = *(const short8*)&Wt[(ng * 32 + 16 + col) * 136 + kc * 32 + quad * 8];
    accR0 = MFMA16(Ar, B0, accR0);
    accI0 = MFMA16(Ai, B0, accI0);
    accR1 = MFMA16(Ar, B1, accR1);
    accI1 = MFMA16(Ai, B1, accI1);
  }
  // epilogue: D col=lane&15, row=quad*4+reg
#pragma unroll
  for (int reg = 0; reg < 4; ++reg) {
    int bb = bh * 32 + mtile * 16 + quad * 4 + reg;
    int o0 = otile * 64 + ng * 32 + col;
    int o1 = o0 + 16;
    *(unsigned int*)(outbuf + chat_q_byte(bb, o0 >> 5, pair * 32 + (o0 & 31), esz)) =
        packbf(accR0[reg], accI0[reg]);
    *(unsigned int*)(outbuf + chat_q_byte(bb, o1 >> 5, pair * 32 + (o1 & 31), esz)) =
        packbf(accR1[reg], accI1[reg]);
  }
}

// ---------------------------------------------------------------------------
// K3: fused Legendre synthesis + inverse DFT + bias. Block=(b, o-quarter):
// 256 blocks x 1024 thr, thread=(j, one o). Pair-minor LDS: chs[ol][pair],
// stb[j][pair] (stride PADC=140) -> 34 ds_read_b128 + 34 broadcast float4
// per thread; 4 waves/SIMD.
// ---------------------------------------------------------------------------
__global__ __launch_bounds__(1024) void k_bwd(char* __restrict__ outbuf,
                                              const void* __restrict__ biasv,
                                              const void* __restrict__ xin) {
  const int fp32m = detect_fp32(xin);
  const int esz = fp32m ? 4 : 2;
  __shared__ __align__(16) unsigned int chs[32 * PADC];    // [ol][pair] re|im bf16
  __shared__ __align__(16) float        stb[32 * PADC];    // [j][pair]
  const int b = blockIdx.x >> 2, oq = blockIdx.x & 3;
  const int t = threadIdx.x;
  for (int i = t; i < NPAIR * 8; i += 1024) {              // 1088 uint4, transpose
    uint4 v = *(const uint4*)(outbuf + chat_q_byte(b, oq, i * 4, esz));
    const int pair = i >> 3, ol0 = (i & 7) * 4;            // u = pair*32 + ol0
    chs[(ol0 + 0) * PADC + pair] = v.x;
    chs[(ol0 + 1) * PADC + pair] = v.y;
    chs[(ol0 + 2) * PADC + pair] = v.z;
    chs[(ol0 + 3) * PADC + pair] = v.w;
  }
  for (int i = t; i < 32 * PADC / 4; i += 1024)            // g_stab already [j][pair]
    ((float4*)stb)[i] = ((const float4*)g_stab)[i];
  const int j = t >> 5, ol = t & 31;
  const int o = oq * 32 + ol;
  const float bv = fp32m ? ((const float*)biasv)[o]
                         : us2f((unsigned int)((const unsigned short*)biasv)[o]);
  __syncthreads();

  float Gr[16], Gi[16];
#pragma unroll
  for (int mm = 0; mm < 16; ++mm) { Gr[mm] = 0.f; Gi[mm] = 0.f; }
  {
    float4 s4 = {0.f, 0.f, 0.f, 0.f};
    uint4  c4 = {0u, 0u, 0u, 0u};
    int pair = 0;
#pragma unroll
    for (int mm = 0; mm < 16; ++mm) {
#pragma unroll
      for (int l = mm; l < 16; ++l) {
        if ((pair & 3) == 0) {                             // folds: pair is unroll-const
          s4 = *(const float4*)&stb[j * PADC + pair];
          c4 = *(const uint4*)&chs[ol * PADC + pair];
        }
        const int r = pair & 3;
        const float        s  = (r == 0) ? s4.x : (r == 1) ? s4.y : (r == 2) ? s4.z : s4.w;
        const unsigned int cv = (r == 0) ? c4.x : (r == 1) ? c4.y : (r == 2) ? c4.z : c4.w;
        Gr[mm] += s * lo_f(cv);
        Gi[mm] += s * hi_f(cv);
        ++pair;
      }
    }
  }
  DEF_TRIG;
#pragma unroll
  for (int pp = 0; pp <= 16; ++pp) {
    float A = 0.f, Bv = 0.f;
#pragma unroll
    for (int mm = 0; mm < 16; ++mm) {
      A  += Gr[mm] * CT[(mm * pp) & 31];
      Bv += Gi[mm] * ST[(mm * pp) & 31];
    }
    const int p2 = (32 - pp) & 31;
    size_t e1 = (size_t)b * 131072 + (size_t)(j * 32 + pp) * 128 + o;
    size_t e2 = (size_t)b * 131072 + (size_t)(j * 32 + p2) * 128 + o;
    if (fp32m) {
      *(float*)(outbuf + e1 * 4) = bv + A - Bv;
      *(float*)(outbuf + e2 * 4) = bv + A + Bv;
    } else {
      *(unsigned short*)(outbuf + e1 * 2) = f2us(bv + A - Bv);
      *(unsigned short*)(outbuf + e2 * 2) = f2us(bv + A + Bv);
    }
  }
}

// ---------------------------------------------------------------------------
extern "C" void kernel_launch(void* const* d_in, const int* in_sizes, int n_in,
                              void* d_out, int out_size, void* d_ws, size_t ws_size,
                              hipStream_t stream) {
  const void* xin  = d_in[0];   // (64,32,32,128) fp32 or bf16 (auto-detected)
  const void* W    = d_in[1];   // (128,16,128)
  const void* bias = d_in[2];   // (128)
  char* out = (char*)d_out;

  hipLaunchKernelGGL(k_init, dim3(NPAIR), dim3(32),   0, stream);
  hipLaunchKernelGGL(k_fwd,  dim3(1024),  dim3(256),  0, stream, xin, out);
  hipLaunchKernelGGL(k_chan, dim3(544),   dim3(256),  0, stream, out, W, xin);
  hipLaunchKernelGGL(k_bwd,  dim3(256),   dim3(1024), 0, stream, out, bias, xin);
}

// Round 3
// 114.311 us; speedup vs baseline: 1.1629x; 1.0330x over previous
//
#include <hip/hip_runtime.h>
#include <hip/hip_bf16.h>
#include <math.h>

// SphConv: B=64, n=32, C_in=C_out=128, L=16, (l,m) pairs l>=m: 136.
// This round: coef intermediate moved to d_ws ([b][pair][c] packed re|im
// uints, 4.5 MB — same-iteration produce/consume, poison-safe). k_chan is
// DELETED: the channel GEMM is fused into k_cb as an MFMA prologue (wave =
// degree l, A-rows = 16 m-slots, re/im share W fragments), writing chat
// directly into the chs LDS array in its final [ol][pair] layout. chat
// never touches global; k_bwd's transpose staging is gone. bf16 pack
// points identical to previous rounds -> identical numerics.

#define NPAIR 136
#define PADC 140   // pair-minor row stride (136 + 4 pad, 16B-aligned rows)

typedef __attribute__((ext_vector_type(8))) short short8;
typedef __attribute__((ext_vector_type(4))) float f32x4;
#define MFMA16(A, B, C) __builtin_amdgcn_mfma_f32_16x16x32_bf16(A, B, C, 0, 0, 0)

static __device__ __forceinline__ float us2f(unsigned int u) {
  union { unsigned int i; float f; } v; v.i = u << 16; return v.f;
}
static __device__ __forceinline__ unsigned short f2us(float f) {
  __hip_bfloat16 h = __float2bfloat16(f);
  return *(unsigned short*)&h;
}
static __device__ __forceinline__ float lo_f(unsigned int pk) {
  union { unsigned int i; float f; } v; v.i = pk << 16; return v.f;
}
static __device__ __forceinline__ float hi_f(unsigned int pk) {
  union { unsigned int i; float f; } v; v.i = pk & 0xffff0000u; return v.f;
}
static __device__ __forceinline__ unsigned int packbf(float a, float b) {
  return (unsigned int)f2us(a) | ((unsigned int)f2us(b) << 16);
}

__device__ __align__(16) unsigned short g_atab_h[NPAIR * 32]; // bf16 Q*wj
__device__ __align__(16) float          g_stab[32 * PADC];    // fp32 Q*scale*(m?2:1), [j][pair]
__device__ int g_tab_ready;                                   // tables memoized across runs

static __device__ __forceinline__ int detect_fp32(const void* xin) {
  const unsigned short* u = (const unsigned short*)xin;
  int lane = threadIdx.x & 63;
  int big = 0;
#pragma unroll
  for (int q = 0; q < 4; ++q) {
    float v = us2f((unsigned int)u[lane * 8 + q * 2]);
    if (!(fabsf(v) <= 1e3f)) big = 1;
  }
  unsigned long long mask = __ballot(big);
  return (__popcll(mask) >= 16) ? 1 : 0;
}

// 32-pt DFT trig tables, cos/sin(2*pi*k/32) — compile-time indices only
#define DEF_TRIG \
  constexpr float CT[32] = { \
    1.0f, 0.98078528f, 0.92387953f, 0.83146961f, 0.70710678f, 0.55557023f, \
    0.38268343f, 0.19509032f, 0.0f, -0.19509032f, -0.38268343f, -0.55557023f, \
    -0.70710678f, -0.83146961f, -0.92387953f, -0.98078528f, -1.0f, \
    -0.98078528f, -0.92387953f, -0.83146961f, -0.70710678f, -0.55557023f, \
    -0.38268343f, -0.19509032f, 0.0f, 0.19509032f, 0.38268343f, 0.55557023f, \
    0.70710678f, 0.83146961f, 0.92387953f, 0.98078528f }; \
  constexpr float ST[32] = { \
    0.0f, 0.19509032f, 0.38268343f, 0.55557023f, 0.70710678f, 0.83146961f, \
    0.92387953f, 0.98078528f, 1.0f, 0.98078528f, 0.92387953f, 0.83146961f, \
    0.70710678f, 0.55557023f, 0.38268343f, 0.19509032f, 0.0f, \
    -0.19509032f, -0.38268343f, -0.55557023f, -0.70710678f, -0.83146961f, \
    -0.92387953f, -0.98078528f, -1.0f, -0.98078528f, -0.92387953f, \
    -0.83146961f, -0.70710678f, -0.55557023f, -0.38268343f, -0.19509032f }

// ---------------------------------------------------------------------------
// K0: tables. One block per (l,m) pair x 32 j. Memoized via g_tab_ready.
// ---------------------------------------------------------------------------
__global__ void k_init() {
  if (g_tab_ready) return;                                 // constants persist
  const int pair = blockIdx.x, j = threadIdx.x;
  int m = 0;
#pragma unroll
  for (int mm = 1; mm < 16; ++mm) {
    int off = mm * 16 - (mm * (mm - 1)) / 2;
    if (off <= pair) m = mm;
  }
  const int l = m + (pair - (m * 16 - (m * (m - 1)) / 2));
  double theta = M_PI * (j + 0.5) / 32.0;
  double x = cos(theta), sx = sin(theta);
  double wj = sx * (M_PI / 32.0) * (2.0 * M_PI / 32.0);
  double pmm = 1.0;
  for (int k = 1; k <= m; ++k) pmm *= -(2.0 * k - 1.0) * sx;
  double p = pmm, pl1 = 0.0, pl2 = 0.0;
  for (int ll = m; ll <= l; ++ll) {
    if (ll == m)          p = pmm;
    else if (ll == m + 1) p = (2.0 * m + 1.0) * x * pmm;
    else                  p = ((2.0 * ll - 1.0) * x * pl1 - (double)(ll + m - 1) * pl2) / (double)(ll - m);
    pl2 = pl1; pl1 = p;
  }
  double r = 1.0;
  for (int k = l - m + 1; k <= l + m; ++k) r *= (double)k;   // (l+m)!/(l-m)!
  double Nlm = sqrt((2.0 * l + 1.0) / (4.0 * M_PI) / r);
  g_atab_h[pair * 32 + j] = f2us((float)(Nlm * p * wj));
  g_stab[j * PADC + pair] = (float)(Nlm * p * (2.0 * M_PI * sqrt(4.0 * M_PI / (2.0 * l + 1.0)))
                                    * (m ? 2.0 : 1.0));
  if (pair == NPAIR - 1 && j == 31) g_tab_ready = 1;       // visible next launch
}

// ---------------------------------------------------------------------------
// K1: fused FFT(phi) + Legendre analysis -> coef (in d_ws). 1024 blocks x
// 256 thr, block=(b, 8-ch group), XCD-swizzled. LDS 35 KB -> 4 blocks/CU.
// Phase 1: one (j,c) DFT per thread. Phase 2: (m,c,jh); atab in LDS (xs
// region reused). coef[b][pair][c] = packed re|im uint in ws.
// ---------------------------------------------------------------------------
__global__ __launch_bounds__(256) void k_fwd(const void* __restrict__ xin,
                                             unsigned int* __restrict__ ws) {
  const int fp32m = detect_fp32(xin);
  __shared__ __align__(16) unsigned short xs[32 * 264];    // [p][j*8+c]; atab after ph1
  __shared__ __align__(16) unsigned int   fsp[128 * 36];   // [(m*8+c)][j] re|im bf16
  const int blk = blockIdx.x;
  const int b = (blk & 7) | (((blk >> 7) & 7) << 3);       // same-b -> same XCD
  const int cq = (blk >> 3) & 15;                          // 8-channel group
  const int t = threadIdx.x;
  // prefetch atab (544 uint4) into registers — latency hides under phase 1
  uint4 at0 = ((const uint4*)g_atab_h)[t];
  uint4 at1 = ((const uint4*)g_atab_h)[t + 256];
  uint4 at2;
  if (t < 32) at2 = ((const uint4*)g_atab_h)[512 + t];
  if (fp32m) {
    const float* xf = (const float*)xin;
#pragma unroll
    for (int it = 0; it < 8; ++it) {
      int i = t + it * 256;                                // [0,2048)
      int s = i >> 1, hf = i & 1;
      float4 v = *(const float4*)(xf + ((size_t)b * 1024 + s) * 128 + cq * 8 + hf * 4);
      int p = s & 31, j = s >> 5;
      *(uint2*)&xs[p * 264 + j * 8 + hf * 4] = make_uint2(packbf(v.x, v.y), packbf(v.z, v.w));
    }
  } else {
    const unsigned short* xh = (const unsigned short*)xin;
#pragma unroll
    for (int it = 0; it < 4; ++it) {
      int s = t + it * 256;                                // [0,1024)
      uint4 v = *(const uint4*)(xh + ((size_t)b * 1024 + s) * 128 + cq * 8);
      int p = s & 31, j = s >> 5;
      *(uint4*)&xs[p * 264 + j * 8] = v;
    }
  }
  __syncthreads();
  {   // phase 1: one 32-pt real DFT per thread. thread = (j, c).
    DEF_TRIG;
    const int j = t >> 3, c = t & 7, rb = j * 8 + c;
    float x0  = us2f((unsigned int)xs[rb]);
    float x16 = us2f((unsigned int)xs[16 * 264 + rb]);
    float sp[16], dm[16];
#pragma unroll
    for (int p = 1; p <= 15; ++p) {
      float a  = us2f((unsigned int)xs[p * 264 + rb]);
      float bq = us2f((unsigned int)xs[(32 - p) * 264 + rb]);
      sp[p] = a + bq; dm[p] = a - bq;
    }
#pragma unroll
    for (int mi = 0; mi < 16; ++mi) {
      float re = x0 + ((mi & 1) ? -x16 : x16);
      float im = 0.f;
#pragma unroll
      for (int p = 1; p <= 15; ++p) {
        re += sp[p] * CT[(mi * p) & 31];
        im -= dm[p] * ST[(mi * p) & 31];
      }
      fsp[(mi * 8 + c) * 36 + j] = packbf(re, im);
    }
  }
  __syncthreads();                                         // xs dead; fsp ready
  ((uint4*)xs)[t] = at0;                                   // stage atab into xs
  ((uint4*)xs)[t + 256] = at1;
  if (t < 32) ((uint4*)xs)[512 + t] = at2;
  __syncthreads();
  {   // phase 2: quadrature. thread = (m, c, jh); F = 4 uint4; atab in LDS.
    const int m = t >> 4, c = (t >> 1) & 7, jh = t & 1;
    const int cg = cq * 8 + c;
    const int base = m * 16 - (m * (m - 1)) / 2;
    uint4 F[4];
#pragma unroll
    for (int q = 0; q < 4; ++q)
      F[q] = *(const uint4*)&fsp[(m * 8 + c) * 36 + jh * 16 + q * 4];
    for (int l = m; l < 16; ++l) {
      int pair = base + (l - m);
      float sr = 0.f, si = 0.f;
#pragma unroll
      for (int q = 0; q < 2; ++q) {
        uint4 a = ((const uint4*)xs)[pair * 4 + jh * 2 + q];
        float a0 = us2f(a.x & 0xffff), a1 = us2f(a.x >> 16);
        float a2 = us2f(a.y & 0xffff), a3 = us2f(a.y >> 16);
        float a4 = us2f(a.z & 0xffff), a5 = us2f(a.z >> 16);
        float a6 = us2f(a.w & 0xffff), a7 = us2f(a.w >> 16);
        uint4 f0 = F[2 * q], f1 = F[2 * q + 1];
        sr += a0 * lo_f(f0.x) + a1 * lo_f(f0.y) + a2 * lo_f(f0.z) + a3 * lo_f(f0.w)
            + a4 * lo_f(f1.x) + a5 * lo_f(f1.y) + a6 * lo_f(f1.z) + a7 * lo_f(f1.w);
        si += a0 * hi_f(f0.x) + a1 * hi_f(f0.y) + a2 * hi_f(f0.z) + a3 * hi_f(f0.w)
            + a4 * hi_f(f1.x) + a5 * hi_f(f1.y) + a6 * hi_f(f1.z) + a7 * hi_f(f1.w);
      }
      sr += __shfl_xor(sr, 1, 64);
      si += __shfl_xor(si, 1, 64);
      if (jh == 0)
        ws[((size_t)b * NPAIR + pair) * 128 + cg] = packbf(sr, si);
    }
  }
}

// ---------------------------------------------------------------------------
// K2: fused channel-GEMM (MFMA) + Legendre synthesis + inverse DFT + bias.
// Block=(b, o-quarter): 256 blocks x 1024 thr (16 waves).
// MFMA prologue: wave w = degree l. A[m=slot s=lane&15][k=c] from ws coef
// (slots s>l zero-padded), B[k=c][n=o=lane&15] from W[:, l, oq*32+...],
// D row=quad*4+reg=slot, col=lane&15=o (verified gfx950 mappings; identical
// frag structure to the old k_chan). Accumulators -> chs[ol][pair] directly.
// Synthesis phase unchanged (34 b128 chs reads + stb broadcast per thread).
// ---------------------------------------------------------------------------
__global__ __launch_bounds__(1024, 4) void k_cb(const unsigned int* __restrict__ ws,
                                                char* __restrict__ outbuf,
                                                const void* __restrict__ Wv,
                                                const void* __restrict__ biasv,
                                                const void* __restrict__ xin) {
  const int fp32m = detect_fp32(xin);
  __shared__ __align__(16) unsigned int chs[32 * PADC];    // [ol][pair] re|im bf16
  __shared__ __align__(16) float        stb[32 * PADC];    // [j][pair]
  const int b = blockIdx.x >> 2, oq = blockIdx.x & 3;
  const int t = threadIdx.x;
  // stage stb (independent of MFMA phase)
  for (int i = t; i < 32 * PADC / 4; i += 1024)
    ((float4*)stb)[i] = ((const float4*)g_stab)[i];
  {   // ---- MFMA phase: wave = degree lw.
    const int lw = t >> 6, lane = t & 63;
    const int col = lane & 15, quad = lane >> 4;
    // A-row slot for loads: s = col; valid if s <= lw.
    const int s = col;
    const int av = (s <= lw);
    const int pv = av ? (s * 16 - (s * (s - 1)) / 2 + (lw - s)) : 0;
    // B fragments: 2 nt x 4 kc from W[c, lw, oq*32 + nt*16 + col]
    short8 Bf[2][4];
    if (fp32m) {
      const float* Wf = (const float*)Wv;
#pragma unroll
      for (int nt = 0; nt < 2; ++nt) {
        const float* wp = Wf + (size_t)lw * 128 + oq * 32 + nt * 16 + col;
#pragma unroll
        for (int kc = 0; kc < 4; ++kc)
#pragma unroll
          for (int r = 0; r < 8; ++r)
            ((unsigned short*)&Bf[nt][kc])[r] =
                f2us(wp[(size_t)(kc * 32 + quad * 8 + r) * 2048]);
      }
    } else {
      const unsigned short* Wh = (const unsigned short*)Wv;
#pragma unroll
      for (int nt = 0; nt < 2; ++nt) {
        const unsigned short* wp = Wh + (size_t)lw * 128 + oq * 32 + nt * 16 + col;
#pragma unroll
        for (int kc = 0; kc < 4; ++kc)
#pragma unroll
          for (int r = 0; r < 8; ++r)
            ((unsigned short*)&Bf[nt][kc])[r] = wp[(size_t)(kc * 32 + quad * 8 + r) * 2048];
      }
    }
    f32x4 aR0 = {0.f, 0.f, 0.f, 0.f}, aI0 = aR0, aR1 = aR0, aI1 = aR0;
#pragma unroll
    for (int kc = 0; kc < 4; ++kc) {
      uint4 u0 = {0u, 0u, 0u, 0u}, u1 = u0;
      if (av) {
        const unsigned int* cp = ws + ((size_t)b * NPAIR + pv) * 128 + kc * 32 + quad * 8;
        u0 = *(const uint4*)cp;
        u1 = *(const uint4*)(cp + 4);
      }
      short8 Ar, Ai;
      Ar[0] = (short)(u0.x & 0xffff); Ai[0] = (short)(u0.x >> 16);
      Ar[1] = (short)(u0.y & 0xffff); Ai[1] = (short)(u0.y >> 16);
      Ar[2] = (short)(u0.z & 0xffff); Ai[2] = (short)(u0.z >> 16);
      Ar[3] = (short)(u0.w & 0xffff); Ai[3] = (short)(u0.w >> 16);
      Ar[4] = (short)(u1.x & 0xffff); Ai[4] = (short)(u1.x >> 16);
      Ar[5] = (short)(u1.y & 0xffff); Ai[5] = (short)(u1.y >> 16);
      Ar[6] = (short)(u1.z & 0xffff); Ai[6] = (short)(u1.z >> 16);
      Ar[7] = (short)(u1.w & 0xffff); Ai[7] = (short)(u1.w >> 16);
      aR0 = MFMA16(Ar, Bf[0][kc], aR0);
      aI0 = MFMA16(Ai, Bf[0][kc], aI0);
      aR1 = MFMA16(Ar, Bf[1][kc], aR1);
      aI1 = MFMA16(Ai, Bf[1][kc], aI1);
    }
    // write chat directly into chs[ol][pair]; D row=quad*4+reg=slot.
#pragma unroll
    for (int reg = 0; reg < 4; ++reg) {
      int slot = quad * 4 + reg;
      if (slot <= lw) {
        int pp_ = slot * 16 - (slot * (slot - 1)) / 2 + (lw - slot);
        chs[(0 * 16 + col) * PADC + pp_] = packbf(aR0[reg], aI0[reg]);
        chs[(1 * 16 + col) * PADC + pp_] = packbf(aR1[reg], aI1[reg]);
      }
    }
  }
  const int j = t >> 5, ol = t & 31;
  const int o = oq * 32 + ol;
  const float bv = fp32m ? ((const float*)biasv)[o]
                         : us2f((unsigned int)((const unsigned short*)biasv)[o]);
  __syncthreads();

  float Gr[16], Gi[16];
#pragma unroll
  for (int mm = 0; mm < 16; ++mm) { Gr[mm] = 0.f; Gi[mm] = 0.f; }
  {
    float4 s4 = {0.f, 0.f, 0.f, 0.f};
    uint4  c4 = {0u, 0u, 0u, 0u};
    int pair = 0;
#pragma unroll
    for (int mm = 0; mm < 16; ++mm) {
#pragma unroll
      for (int l = mm; l < 16; ++l) {
        if ((pair & 3) == 0) {                             // folds: pair is unroll-const
          s4 = *(const float4*)&stb[j * PADC + pair];
          c4 = *(const uint4*)&chs[ol * PADC + pair];
        }
        const int r = pair & 3;
        const float        s  = (r == 0) ? s4.x : (r == 1) ? s4.y : (r == 2) ? s4.z : s4.w;
        const unsigned int cv = (r == 0) ? c4.x : (r == 1) ? c4.y : (r == 2) ? c4.z : c4.w;
        Gr[mm] += s * lo_f(cv);
        Gi[mm] += s * hi_f(cv);
        ++pair;
      }
    }
  }
  DEF_TRIG;
#pragma unroll
  for (int pp = 0; pp <= 16; ++pp) {
    float A = 0.f, Bv = 0.f;
#pragma unroll
    for (int mm = 0; mm < 16; ++mm) {
      A  += Gr[mm] * CT[(mm * pp) & 31];
      Bv += Gi[mm] * ST[(mm * pp) & 31];
    }
    const int p2 = (32 - pp) & 31;
    size_t e1 = (size_t)b * 131072 + (size_t)(j * 32 + pp) * 128 + o;
    size_t e2 = (size_t)b * 131072 + (size_t)(j * 32 + p2) * 128 + o;
    if (fp32m) {
      *(float*)(outbuf + e1 * 4) = bv + A - Bv;
      *(float*)(outbuf + e2 * 4) = bv + A + Bv;
    } else {
      *(unsigned short*)(outbuf + e1 * 2) = f2us(bv + A - Bv);
      *(unsigned short*)(outbuf + e2 * 2) = f2us(bv + A + Bv);
    }
  }
}

// ---------------------------------------------------------------------------
extern "C" void kernel_launch(void* const* d_in, const int* in_sizes, int n_in,
                              void* d_out, int out_size, void* d_ws, size_t ws_size,
                              hipStream_t stream) {
  const void* xin  = d_in[0];   // (64,32,32,128) fp32 or bf16 (auto-detected)
  const void* W    = d_in[1];   // (128,16,128)
  const void* bias = d_in[2];   // (128)
  char* out = (char*)d_out;
  unsigned int* ws = (unsigned int*)d_ws;  // coef: 64*136*128 uints = 4.5 MB

  hipLaunchKernelGGL(k_init, dim3(NPAIR), dim3(32),   0, stream);
  hipLaunchKernelGGL(k_fwd,  dim3(1024),  dim3(256),  0, stream, xin, ws);
  hipLaunchKernelGGL(k_cb,   dim3(256),   dim3(1024), 0, stream, ws, out, W, bias, xin);
}

// Round 4
// 111.014 us; speedup vs baseline: 1.1974x; 1.0297x over previous
//
#include <hip/hip_runtime.h>
#include <hip/hip_bf16.h>
#include <math.h>

// SphConv: B=64, n=32, C_in=C_out=128, L=16, (l,m) pairs l>=m: 136.
// coef intermediate in d_ws ([b][pair][c] packed re|im uints, 4.5 MB,
// same-iteration produce/consume). Wt[l][o][c] bf16 transpose of W at
// ws+8MB, produced by a tail on k_fwd blocks (W changes per call — must
// not be memoized). k_cb fuses channel-GEMM (MFMA) + synthesis + iDFT.
// This round: k_fwd phase 2 (Legendre quadrature) is now MFMA per m
// (M=l-slot, K=j=32, N=16=8c x re/im) — replaces ~1600 VALU ops/thread;
// k_cb B-fragments load coalesced b128 from Wt instead of 64 scalar
// stride-8KB W loads + f2us per thread.

#define NPAIR 136
#define PADC 140   // pair-minor row stride (136 + 4 pad, 16B-aligned rows)
#define WT_OFF (8u << 20)   // byte offset of Wt[l][o][c] bf16 in d_ws

typedef __attribute__((ext_vector_type(8))) short short8;
typedef __attribute__((ext_vector_type(4))) float f32x4;
#define MFMA16(A, B, C) __builtin_amdgcn_mfma_f32_16x16x32_bf16(A, B, C, 0, 0, 0)

static __device__ __forceinline__ float us2f(unsigned int u) {
  union { unsigned int i; float f; } v; v.i = u << 16; return v.f;
}
static __device__ __forceinline__ unsigned short f2us(float f) {
  __hip_bfloat16 h = __float2bfloat16(f);
  return *(unsigned short*)&h;
}
static __device__ __forceinline__ float lo_f(unsigned int pk) {
  union { unsigned int i; float f; } v; v.i = pk << 16; return v.f;
}
static __device__ __forceinline__ float hi_f(unsigned int pk) {
  union { unsigned int i; float f; } v; v.i = pk & 0xffff0000u; return v.f;
}
static __device__ __forceinline__ unsigned int packbf(float a, float b) {
  return (unsigned int)f2us(a) | ((unsigned int)f2us(b) << 16);
}

__device__ __align__(16) unsigned short g_atab_h[NPAIR * 32]; // bf16 Q*wj
__device__ __align__(16) float          g_stab[32 * PADC];    // fp32 Q*scale*(m?2:1), [j][pair]
__device__ int g_tab_ready;                                   // tables memoized across runs

static __device__ __forceinline__ int detect_fp32(const void* xin) {
  const unsigned short* u = (const unsigned short*)xin;
  int lane = threadIdx.x & 63;
  int big = 0;
#pragma unroll
  for (int q = 0; q < 4; ++q) {
    float v = us2f((unsigned int)u[lane * 8 + q * 2]);
    if (!(fabsf(v) <= 1e3f)) big = 1;
  }
  unsigned long long mask = __ballot(big);
  return (__popcll(mask) >= 16) ? 1 : 0;
}

// 32-pt DFT trig tables, cos/sin(2*pi*k/32) — compile-time indices only
#define DEF_TRIG \
  constexpr float CT[32] = { \
    1.0f, 0.98078528f, 0.92387953f, 0.83146961f, 0.70710678f, 0.55557023f, \
    0.38268343f, 0.19509032f, 0.0f, -0.19509032f, -0.38268343f, -0.55557023f, \
    -0.70710678f, -0.83146961f, -0.92387953f, -0.98078528f, -1.0f, \
    -0.98078528f, -0.92387953f, -0.83146961f, -0.70710678f, -0.55557023f, \
    -0.38268343f, -0.19509032f, 0.0f, 0.19509032f, 0.38268343f, 0.55557023f, \
    0.70710678f, 0.83146961f, 0.92387953f, 0.98078528f }; \
  constexpr float ST[32] = { \
    0.0f, 0.19509032f, 0.38268343f, 0.55557023f, 0.70710678f, 0.83146961f, \
    0.92387953f, 0.98078528f, 1.0f, 0.98078528f, 0.92387953f, 0.83146961f, \
    0.70710678f, 0.55557023f, 0.38268343f, 0.19509032f, 0.0f, \
    -0.19509032f, -0.38268343f, -0.55557023f, -0.70710678f, -0.83146961f, \
    -0.92387953f, -0.98078528f, -1.0f, -0.98078528f, -0.92387953f, \
    -0.83146961f, -0.70710678f, -0.55557023f, -0.38268343f, -0.19509032f }

// ---------------------------------------------------------------------------
// K0: tables. One block per (l,m) pair x 32 j. Memoized via g_tab_ready
// (input-independent constants only).
// ---------------------------------------------------------------------------
__global__ void k_init() {
  if (g_tab_ready) return;                                 // constants persist
  const int pair = blockIdx.x, j = threadIdx.x;
  int m = 0;
#pragma unroll
  for (int mm = 1; mm < 16; ++mm) {
    int off = mm * 16 - (mm * (mm - 1)) / 2;
    if (off <= pair) m = mm;
  }
  const int l = m + (pair - (m * 16 - (m * (m - 1)) / 2));
  double theta = M_PI * (j + 0.5) / 32.0;
  double x = cos(theta), sx = sin(theta);
  double wj = sx * (M_PI / 32.0) * (2.0 * M_PI / 32.0);
  double pmm = 1.0;
  for (int k = 1; k <= m; ++k) pmm *= -(2.0 * k - 1.0) * sx;
  double p = pmm, pl1 = 0.0, pl2 = 0.0;
  for (int ll = m; ll <= l; ++ll) {
    if (ll == m)          p = pmm;
    else if (ll == m + 1) p = (2.0 * m + 1.0) * x * pmm;
    else                  p = ((2.0 * ll - 1.0) * x * pl1 - (double)(ll + m - 1) * pl2) / (double)(ll - m);
    pl2 = pl1; pl1 = p;
  }
  double r = 1.0;
  for (int k = l - m + 1; k <= l + m; ++k) r *= (double)k;   // (l+m)!/(l-m)!
  double Nlm = sqrt((2.0 * l + 1.0) / (4.0 * M_PI) / r);
  g_atab_h[pair * 32 + j] = f2us((float)(Nlm * p * wj));
  g_stab[j * PADC + pair] = (float)(Nlm * p * (2.0 * M_PI * sqrt(4.0 * M_PI / (2.0 * l + 1.0)))
                                    * (m ? 2.0 : 1.0));
  if (pair == NPAIR - 1 && j == 31) g_tab_ready = 1;       // visible next launch
}

// ---------------------------------------------------------------------------
// K1: fused FFT(phi) + Legendre analysis -> coef (in d_ws). 1024 blocks x
// 256 thr, block=(b, 8-ch group), XCD-swizzled. LDS 35 KB -> 4 blocks/CU.
// Phase 1: one (j,c) DFT per thread -> fsp2[m][n=2c+ri][j] u16.
// Phase 2: MFMA per m (wave wv handles m=wv*4..+3): A=atab (LDS, staged
// into dead xs region), B=fsp2, D -> packed coef uints in ws.
// Tail (blk<512): transpose W -> Wt[l][o][c] bf16 in ws (per-call).
// ---------------------------------------------------------------------------
__global__ __launch_bounds__(256) void k_fwd(const void* __restrict__ xin,
                                             unsigned int* __restrict__ ws,
                                             const void* __restrict__ Wv) {
  const int fp32m = detect_fp32(xin);
  __shared__ __align__(16) unsigned short xs[32 * 264];    // [p][j*8+c]; atab after ph1
  __shared__ __align__(16) unsigned short fsp2[16 * 16 * 36]; // [m][n][j] 18 KB
  const int blk = blockIdx.x;
  const int b = (blk & 7) | (((blk >> 7) & 7) << 3);       // same-b -> same XCD
  const int cq = (blk >> 3) & 15;                          // 8-channel group
  const int t = threadIdx.x;
  // prefetch atab (544 uint4) into registers — latency hides under phase 1
  uint4 at0 = ((const uint4*)g_atab_h)[t];
  uint4 at1 = ((const uint4*)g_atab_h)[t + 256];
  uint4 at2;
  if (t < 32) at2 = ((const uint4*)g_atab_h)[512 + t];
  // W -> Wt transpose tail work, distributed over blocks 0..511 (2 c/thread)
  if (blk < 512) {
    const int loe = blk * 4 + (t >> 6);                    // l*128 + o
    const int l = loe >> 7, o = loe & 127, c0 = (t & 63) * 2;
    unsigned int pk;
    if (fp32m) {
      const float* Wf = (const float*)Wv;
      pk = packbf(Wf[(size_t)c0 * 2048 + l * 128 + o],
                  Wf[(size_t)(c0 + 1) * 2048 + l * 128 + o]);
    } else {
      const unsigned short* Wh = (const unsigned short*)Wv;
      pk = (unsigned int)Wh[(size_t)c0 * 2048 + l * 128 + o]
         | ((unsigned int)Wh[(size_t)(c0 + 1) * 2048 + l * 128 + o] << 16);
    }
    ((unsigned int*)((char*)ws + WT_OFF))[(size_t)loe * 64 + (c0 >> 1)] = pk;
  }
  if (fp32m) {
    const float* xf = (const float*)xin;
#pragma unroll
    for (int it = 0; it < 8; ++it) {
      int i = t + it * 256;                                // [0,2048)
      int s = i >> 1, hf = i & 1;
      float4 v = *(const float4*)(xf + ((size_t)b * 1024 + s) * 128 + cq * 8 + hf * 4);
      int p = s & 31, j = s >> 5;
      *(uint2*)&xs[p * 264 + j * 8 + hf * 4] = make_uint2(packbf(v.x, v.y), packbf(v.z, v.w));
    }
  } else {
    const unsigned short* xh = (const unsigned short*)xin;
#pragma unroll
    for (int it = 0; it < 4; ++it) {
      int s = t + it * 256;                                // [0,1024)
      uint4 v = *(const uint4*)(xh + ((size_t)b * 1024 + s) * 128 + cq * 8);
      int p = s & 31, j = s >> 5;
      *(uint4*)&xs[p * 264 + j * 8] = v;
    }
  }
  __syncthreads();
  {   // phase 1: one 32-pt real DFT per thread. thread = (j, c).
    DEF_TRIG;
    const int j = t >> 3, c = t & 7, rb = j * 8 + c;
    float x0  = us2f((unsigned int)xs[rb]);
    float x16 = us2f((unsigned int)xs[16 * 264 + rb]);
    float sp[16], dm[16];
#pragma unroll
    for (int p = 1; p <= 15; ++p) {
      float a  = us2f((unsigned int)xs[p * 264 + rb]);
      float bq = us2f((unsigned int)xs[(32 - p) * 264 + rb]);
      sp[p] = a + bq; dm[p] = a - bq;
    }
#pragma unroll
    for (int mi = 0; mi < 16; ++mi) {
      float re = x0 + ((mi & 1) ? -x16 : x16);
      float im = 0.f;
#pragma unroll
      for (int p = 1; p <= 15; ++p) {
        re += sp[p] * CT[(mi * p) & 31];
        im -= dm[p] * ST[(mi * p) & 31];
      }
      fsp2[(mi * 16 + 2 * c + 0) * 36 + j] = f2us(re);
      fsp2[(mi * 16 + 2 * c + 1) * 36 + j] = f2us(im);
    }
  }
  __syncthreads();                                         // xs dead; fsp2 ready
  ((uint4*)xs)[t] = at0;                                   // stage atab into xs
  ((uint4*)xs)[t + 256] = at1;
  if (t < 32) ((uint4*)xs)[512 + t] = at2;
  __syncthreads();
  {   // phase 2: MFMA quadrature. wave wv -> m = wv*4..wv*4+3.
    const int wv = t >> 6, lane = t & 63;
    const int n = lane & 15, quad = lane >> 4;
    const unsigned short* atab = (const unsigned short*)xs;
#pragma unroll
    for (int mi4 = 0; mi4 < 4; ++mi4) {
      const int mi = wv * 4 + mi4;
      const int base = mi * 16 - (mi * (mi - 1)) / 2;
      // A[row=l-slot=n][k=j]: b128 from atab; rows beyond 16-mi are junk
      // (values from later pairs / stale xs) — affects only discarded D rows.
      short8 A = *(const short8*)&atab[(base + n) * 32 + quad * 8];
      // B[k=j=quad*8+r][col=n]: b128 from fsp2[m][n][j]
      short8 Bv = *(const short8*)&fsp2[(mi * 16 + n) * 36 + quad * 8];
      f32x4 d = {0.f, 0.f, 0.f, 0.f};
      d = MFMA16(A, Bv, d);
      // D row=quad*4+reg=l-slot, col=n (n even: re of c=n/2; odd: im).
#pragma unroll
      for (int reg = 0; reg < 4; ++reg) {
        float other = __shfl_xor(d[reg], 1, 64);
        int slot = quad * 4 + reg;
        if (!(n & 1) && slot < 16 - mi)
          ws[((size_t)b * NPAIR + base + slot) * 128 + cq * 8 + (n >> 1)] =
              packbf(d[reg], other);
      }
    }
  }
}

// ---------------------------------------------------------------------------
// K2: fused channel-GEMM (MFMA) + Legendre synthesis + inverse DFT + bias.
// Block=(b, o-quarter): 256 blocks x 1024 thr (16 waves).
// MFMA prologue: wave w = degree l. A from ws coef, B from Wt (coalesced
// b128), D -> chs[ol][pair] directly. Synthesis: 34 b128 chs reads + stb
// broadcast per thread, literal-twiddle iDFT, bias, store.
// ---------------------------------------------------------------------------
__global__ __launch_bounds__(1024, 4) void k_cb(const unsigned int* __restrict__ ws,
                                                char* __restrict__ outbuf,
                                                const unsigned short* __restrict__ wt,
                                                const void* __restrict__ biasv,
                                                const void* __restrict__ xin) {
  const int fp32m = detect_fp32(xin);
  __shared__ __align__(16) unsigned int chs[32 * PADC];    // [ol][pair] re|im bf16
  __shared__ __align__(16) float        stb[32 * PADC];    // [j][pair]
  const int b = blockIdx.x >> 2, oq = blockIdx.x & 3;
  const int t = threadIdx.x;
  // stage stb (independent of MFMA phase)
  for (int i = t; i < 32 * PADC / 4; i += 1024)
    ((float4*)stb)[i] = ((const float4*)g_stab)[i];
  {   // ---- MFMA phase: wave = degree lw.
    const int lw = t >> 6, lane = t & 63;
    const int col = lane & 15, quad = lane >> 4;
    const int s = col;
    const int av = (s <= lw);
    const int pv = av ? (s * 16 - (s * (s - 1)) / 2 + (lw - s)) : 0;
    // B fragments: 2 nt x 4 kc, coalesced b128 from Wt[lw][o][c]
    short8 Bf[2][4];
#pragma unroll
    for (int nt = 0; nt < 2; ++nt) {
      const unsigned short* wp = wt + ((size_t)lw * 128 + oq * 32 + nt * 16 + col) * 128;
#pragma unroll
      for (int kc = 0; kc < 4; ++kc)
        Bf[nt][kc] = *(const short8*)(wp + kc * 32 + quad * 8);
    }
    f32x4 aR0 = {0.f, 0.f, 0.f, 0.f}, aI0 = aR0, aR1 = aR0, aI1 = aR0;
#pragma unroll
    for (int kc = 0; kc < 4; ++kc) {
      uint4 u0 = {0u, 0u, 0u, 0u}, u1 = u0;
      if (av) {
        const unsigned int* cp = ws + ((size_t)b * NPAIR + pv) * 128 + kc * 32 + quad * 8;
        u0 = *(const uint4*)cp;
        u1 = *(const uint4*)(cp + 4);
      }
      short8 Ar, Ai;
      Ar[0] = (short)(u0.x & 0xffff); Ai[0] = (short)(u0.x >> 16);
      Ar[1] = (short)(u0.y & 0xffff); Ai[1] = (short)(u0.y >> 16);
      Ar[2] = (short)(u0.z & 0xffff); Ai[2] = (short)(u0.z >> 16);
      Ar[3] = (short)(u0.w & 0xffff); Ai[3] = (short)(u0.w >> 16);
      Ar[4] = (short)(u1.x & 0xffff); Ai[4] = (short)(u1.x >> 16);
      Ar[5] = (short)(u1.y & 0xffff); Ai[5] = (short)(u1.y >> 16);
      Ar[6] = (short)(u1.z & 0xffff); Ai[6] = (short)(u1.z >> 16);
      Ar[7] = (short)(u1.w & 0xffff); Ai[7] = (short)(u1.w >> 16);
      aR0 = MFMA16(Ar, Bf[0][kc], aR0);
      aI0 = MFMA16(Ai, Bf[0][kc], aI0);
      aR1 = MFMA16(Ar, Bf[1][kc], aR1);
      aI1 = MFMA16(Ai, Bf[1][kc], aI1);
    }
    // write chat directly into chs[ol][pair]; D row=quad*4+reg=slot.
#pragma unroll
    for (int reg = 0; reg < 4; ++reg) {
      int slot = quad * 4 + reg;
      if (slot <= lw) {
        int pp_ = slot * 16 - (slot * (slot - 1)) / 2 + (lw - slot);
        chs[(0 * 16 + col) * PADC + pp_] = packbf(aR0[reg], aI0[reg]);
        chs[(1 * 16 + col) * PADC + pp_] = packbf(aR1[reg], aI1[reg]);
      }
    }
  }
  const int j = t >> 5, ol = t & 31;
  const int o = oq * 32 + ol;
  const float bv = fp32m ? ((const float*)biasv)[o]
                         : us2f((unsigned int)((const unsigned short*)biasv)[o]);
  __syncthreads();

  float Gr[16], Gi[16];
#pragma unroll
  for (int mm = 0; mm < 16; ++mm) { Gr[mm] = 0.f; Gi[mm] = 0.f; }
  {
    float4 s4 = {0.f, 0.f, 0.f, 0.f};
    uint4  c4 = {0u, 0u, 0u, 0u};
    int pair = 0;
#pragma unroll
    for (int mm = 0; mm < 16; ++mm) {
#pragma unroll
      for (int l = mm; l < 16; ++l) {
        if ((pair & 3) == 0) {                             // folds: pair is unroll-const
          s4 = *(const float4*)&stb[j * PADC + pair];
          c4 = *(const uint4*)&chs[ol * PADC + pair];
        }
        const int r = pair & 3;
        const float        s  = (r == 0) ? s4.x : (r == 1) ? s4.y : (r == 2) ? s4.z : s4.w;
        const unsigned int cv = (r == 0) ? c4.x : (r == 1) ? c4.y : (r == 2) ? c4.z : c4.w;
        Gr[mm] += s * lo_f(cv);
        Gi[mm] += s * hi_f(cv);
        ++pair;
      }
    }
  }
  DEF_TRIG;
#pragma unroll
  for (int pp = 0; pp <= 16; ++pp) {
    float A = 0.f, Bv = 0.f;
#pragma unroll
    for (int mm = 0; mm < 16; ++mm) {
      A  += Gr[mm] * CT[(mm * pp) & 31];
      Bv += Gi[mm] * ST[(mm * pp) & 31];
    }
    const int p2 = (32 - pp) & 31;
    size_t e1 = (size_t)b * 131072 + (size_t)(j * 32 + pp) * 128 + o;
    size_t e2 = (size_t)b * 131072 + (size_t)(j * 32 + p2) * 128 + o;
    if (fp32m) {
      *(float*)(outbuf + e1 * 4) = bv + A - Bv;
      *(float*)(outbuf + e2 * 4) = bv + A + Bv;
    } else {
      *(unsigned short*)(outbuf + e1 * 2) = f2us(bv + A - Bv);
      *(unsigned short*)(outbuf + e2 * 2) = f2us(bv + A + Bv);
    }
  }
}

// ---------------------------------------------------------------------------
extern "C" void kernel_launch(void* const* d_in, const int* in_sizes, int n_in,
                              void* d_out, int out_size, void* d_ws, size_t ws_size,
                              hipStream_t stream) {
  const void* xin  = d_in[0];   // (64,32,32,128) fp32 or bf16 (auto-detected)
  const void* W    = d_in[1];   // (128,16,128)
  const void* bias = d_in[2];   // (128)
  char* out = (char*)d_out;
  unsigned int* ws = (unsigned int*)d_ws;  // coef 4.5 MB @0; Wt bf16 @ +8MB
  const unsigned short* wt = (const unsigned short*)((char*)d_ws + WT_OFF);

  hipLaunchKernelGGL(k_init, dim3(NPAIR), dim3(32),   0, stream);
  hipLaunchKernelGGL(k_fwd,  dim3(1024),  dim3(256),  0, stream, xin, ws, W);
  hipLaunchKernelGGL(k_cb,   dim3(256),   dim3(1024), 0, stream, ws, out, wt, bias, xin);
}